// Round 5
// baseline (320.027 us; speedup 1.0000x reference)
//
#include <hip/hip_runtime.h>

// Problem constants (from reference setup_inputs)
#define BATCH 4
#define CH    256
#define FH    200
#define FW    200
#define NROI  1024
#define PLANE (FH * FW)     // 40000 floats = 160000 B -> fits 160 KiB LDS
#define POOL  7
#define NWAVE 16            // 1024 threads

// One workgroup per (image b, channel c) plane.
// Phase 1: stage the whole 200x200 plane HBM->LDS, coalesced float4
//          (feature map read EXACTLY once: 164 MB total, vs 284 MB scattered
//          fetch in the previous global-gather version).
// Phase 2: wave-strided scan over rois; rois of other images skipped by a
//          wave-uniform branch. Per matching roi: per-lane bilinear gather
//          of 4 corners from LDS, 2x2 avg-pool via two shfl_down, store.
__global__ __launch_bounds__(1024, 1) void roialign_lds_kernel(
    const float* __restrict__ feat,   // (B, C, H, W) f32
    const float* __restrict__ rois,   // (N, 5) f32
    const float* __restrict__ scale_p,
    float* __restrict__ out)          // (N, C, 7, 7) f32
{
    __shared__ float splane[PLANE];   // 160000 B

    const int c   = blockIdx.x;
    const int b   = blockIdx.y;
    const int tid = threadIdx.x;

    // ---- phase 1: stage full plane into LDS (coalesced) -------------------
    {
        const float4* __restrict__ src =
            (const float4*)(feat + ((size_t)b * CH + c) * PLANE);
        float4* dst = (float4*)splane;
        for (int i = tid; i < PLANE / 4; i += 1024)   // 10000 float4s
            dst[i] = src[i];
    }
    __syncthreads();

    // ---- phase 2: process this image's rois -------------------------------
    const float scale = scale_p[0];
    const int wave = tid >> 6;
    const int lane = tid & 63;
    const int ph   = lane >> 3;   // sample row 0..7
    const int pw   = lane & 7;    // sample col 0..7
    const bool do_store = (ph < POOL) && (pw < POOL);

    for (int n = wave; n < NROI; n += NWAVE) {
        const int rb = (int)rois[n * 5 + 0];
        if (rb != b) continue;                    // wave-uniform skip

        const float x1 = rois[n * 5 + 1] * scale;
        const float y1 = rois[n * 5 + 2] * scale;
        const float x2 = rois[n * 5 + 3] * scale;
        const float y2 = rois[n * 5 + 4] * scale;

        // matches reference: max(span+1, 0) / (AH-1)
        const float bin_h = fmaxf(y2 - y1 + 1.0f, 0.0f) * (1.0f / 7.0f);
        const float bin_w = fmaxf(x2 - x1 + 1.0f, 0.0f) * (1.0f / 7.0f);

        const float h    = y1 + (float)ph * bin_h;
        const float w    = x1 + (float)pw * bin_w;
        const float hs_f = fminf(floorf(h), (float)(FH - 2));
        const float ws_f = fminf(floorf(w), (float)(FW - 2));
        const float hr   = h - hs_f;          // may exceed [0,1] at edges (ref too)
        const float wr   = w - ws_f;
        const int   hi   = (int)fmaxf(hs_f, 0.0f);   // [0,198]
        const int   wi   = (int)fmaxf(ws_f, 0.0f);   // [0,198]
        const bool  valid = (h >= 0.0f) && (h < (float)FH) &&
                            (w >= 0.0f) && (w < (float)FW);
        const float m = valid ? 0.25f : 0.0f; // fold validity + pool scale

        const float w00 = (1.0f - hr) * (1.0f - wr) * m;
        const float w01 = (1.0f - hr) * wr * m;
        const float w10 = hr * (1.0f - wr) * m;
        const float w11 = hr * wr * m;

        // LDS gather: off/off+1 and off+FW/off+FW+1 pair into ds_read2_b32
        const int off = hi * FW + wi;
        const float g00 = splane[off];
        const float g01 = splane[off + 1];
        const float g10 = splane[off + FW];
        const float g11 = splane[off + FW + 1];

        float v  = g00 * w00 + g01 * w01 + g10 * w10 + g11 * w11;

        // 2x2 avg-pool across the 8x8 sample grid: lanes l, l+1, l+8, l+9
        float s1 = v + __shfl_down(v, 1, 64);
        float s2 = s1 + __shfl_down(s1, 8, 64);

        if (do_store)
            __builtin_nontemporal_store(
                s2, out + ((size_t)n * CH + c) * (POOL * POOL) + ph * POOL + pw);
    }
}

extern "C" void kernel_launch(void* const* d_in, const int* in_sizes, int n_in,
                              void* d_out, int out_size, void* d_ws, size_t ws_size,
                              hipStream_t stream) {
    const float* feat    = (const float*)d_in[0];  // (4,256,200,200) f32
    const float* rois    = (const float*)d_in[1];  // (1024,5) f32
    const float* scale_p = (const float*)d_in[2];  // scalar f32
    float*       out     = (float*)d_out;          // (1024,256,7,7) f32
    (void)in_sizes; (void)n_in; (void)out_size; (void)d_ws; (void)ws_size;

    dim3 grid(CH, BATCH);   // one wg per (channel, image) plane = 1024 wgs
    dim3 block(1024);
    hipLaunchKernelGGL(roialign_lds_kernel, grid, block, 0, stream,
                       feat, rois, scale_p, out);
}

// Round 6
// 273.120 us; speedup vs baseline: 1.1717x; 1.1717x over previous
//
#include <hip/hip_runtime.h>

// Problem constants (from reference setup_inputs)
#define BATCH 4
#define CH    256
#define FH    200
#define FW    200
#define NROI  1024
#define PLANE (FH * FW)     // 40000 floats = 160000 B -> fits 160 KiB LDS
#define POOL  7
#define NWAVE 16            // 1024 threads

// ---------- pre-kernel: build per-image compacted roi index lists ----------
// ws layout: int cnt[BATCH]; int idx[BATCH][NROI];
__global__ __launch_bounds__(1024) void build_roi_lists(
    const float* __restrict__ rois, int* __restrict__ cnt, int* __restrict__ idx)
{
    __shared__ int lcnt[BATCH];
    const int tid = threadIdx.x;
    if (tid < BATCH) lcnt[tid] = 0;
    __syncthreads();
    const int b = (int)rois[tid * 5];
    const int pos = atomicAdd(&lcnt[b], 1);
    idx[(b << 10) + pos] = tid;
    __syncthreads();
    if (tid < BATCH) cnt[tid] = lcnt[tid];
}

// ---------- main kernel: one wg per (channel, image) plane -----------------
// Phase 1: stage the whole 200x200 plane HBM->LDS (coalesced float4).
// Phase 2: iterate ONLY this image's rois via the compacted list (no scan
// misses); roi index forced to SGPR so roi-row reads are scalar loads;
// unroll 2 lets independent roi iterations pipeline.
__global__ __launch_bounds__(1024, 1) void roialign_lds_kernel(
    const float* __restrict__ feat,   // (B, C, H, W) f32
    const float* __restrict__ rois,   // (N, 5) f32
    const float* __restrict__ scale_p,
    const int*   __restrict__ cnt,    // [BATCH]
    const int*   __restrict__ idx,    // [BATCH][NROI]
    float* __restrict__ out)          // (N, C, 7, 7) f32
{
    __shared__ float splane[PLANE];   // 160000 B

    const int c   = blockIdx.x;
    const int b   = blockIdx.y;
    const int tid = threadIdx.x;

    // ---- phase 1: stage full plane into LDS (coalesced) -------------------
    {
        const float4* __restrict__ src =
            (const float4*)(feat + ((size_t)b * CH + c) * PLANE);
        float4* dst = (float4*)splane;
        for (int i = tid; i < PLANE / 4; i += 1024)   // 10000 float4s
            dst[i] = src[i];
    }
    __syncthreads();

    // ---- phase 2: this image's rois only ----------------------------------
    const float scale = scale_p[0];
    const int wave = tid >> 6;
    const int lane = tid & 63;
    const int ph   = lane >> 3;   // sample row 0..7
    const int pw   = lane & 7;    // sample col 0..7
    const bool do_store = (ph < POOL) && (pw < POOL);

    const int cntb = __builtin_amdgcn_readfirstlane(cnt[b]);

#pragma unroll 2
    for (int i = wave; i < cntb; i += NWAVE) {
        int n = idx[(b << 10) + i];
        n = __builtin_amdgcn_readfirstlane(n);   // SGPR -> scalar roi loads

        const float x1 = rois[n * 5 + 1] * scale;
        const float y1 = rois[n * 5 + 2] * scale;
        const float x2 = rois[n * 5 + 3] * scale;
        const float y2 = rois[n * 5 + 4] * scale;

        // matches reference: max(span+1, 0) / (AH-1)
        const float bin_h = fmaxf(y2 - y1 + 1.0f, 0.0f) * (1.0f / 7.0f);
        const float bin_w = fmaxf(x2 - x1 + 1.0f, 0.0f) * (1.0f / 7.0f);

        const float h    = y1 + (float)ph * bin_h;
        const float w    = x1 + (float)pw * bin_w;
        const float hs_f = fminf(floorf(h), (float)(FH - 2));
        const float ws_f = fminf(floorf(w), (float)(FW - 2));
        const float hr   = h - hs_f;          // may exceed [0,1] at edges (ref too)
        const float wr   = w - ws_f;
        const int   hi   = (int)fmaxf(hs_f, 0.0f);   // [0,198]
        const int   wi   = (int)fmaxf(ws_f, 0.0f);   // [0,198]
        const bool  valid = (h >= 0.0f) && (h < (float)FH) &&
                            (w >= 0.0f) && (w < (float)FW);
        const float m = valid ? 0.25f : 0.0f; // fold validity + pool scale

        const float w00 = (1.0f - hr) * (1.0f - wr) * m;
        const float w01 = (1.0f - hr) * wr * m;
        const float w10 = hr * (1.0f - wr) * m;
        const float w11 = hr * wr * m;

        // LDS gather: pairs fold into ds_read2_b32
        const int off = hi * FW + wi;
        const float g00 = splane[off];
        const float g01 = splane[off + 1];
        const float g10 = splane[off + FW];
        const float g11 = splane[off + FW + 1];

        float v  = g00 * w00 + g01 * w01 + g10 * w10 + g11 * w11;

        // 2x2 avg-pool across the 8x8 sample grid: lanes l, l+1, l+8, l+9
        float s1 = v + __shfl_down(v, 1, 64);
        float s2 = s1 + __shfl_down(s1, 8, 64);

        if (do_store)
            __builtin_nontemporal_store(
                s2, out + ((size_t)n * CH + c) * (POOL * POOL) + ph * POOL + pw);
    }
}

// ---------- fallback (R3 global-gather) if ws is too small -----------------
#define CGROUPS 8
#define CH_PER_WAVE 8
__global__ __launch_bounds__(256) void roialign_gather_kernel(
    const float* __restrict__ feat, const float* __restrict__ rois,
    const float* __restrict__ scale_p, float* __restrict__ out)
{
    const int n = blockIdx.x, g = blockIdx.y, tid = threadIdx.x;
    const int wave = tid >> 6, lane = tid & 63;
    const int ph = lane >> 3, pw = lane & 7;
    const float scale = scale_p[0];
    const int   b  = (int)rois[n * 5 + 0];
    const float x1 = rois[n * 5 + 1] * scale, y1 = rois[n * 5 + 2] * scale;
    const float x2 = rois[n * 5 + 3] * scale, y2 = rois[n * 5 + 4] * scale;
    const float bin_h = fmaxf(y2 - y1 + 1.0f, 0.0f) / 7.0f;
    const float bin_w = fmaxf(x2 - x1 + 1.0f, 0.0f) / 7.0f;
    const float h = y1 + (float)ph * bin_h, w = x1 + (float)pw * bin_w;
    const float hs_f = fminf(floorf(h), (float)(FH - 2));
    const float ws_f = fminf(floorf(w), (float)(FW - 2));
    const float hr = h - hs_f, wr = w - ws_f;
    const int hi = (int)fmaxf(hs_f, 0.0f), wi = (int)fmaxf(ws_f, 0.0f);
    const bool valid = (h >= 0.0f) && (h < (float)FH) && (w >= 0.0f) && (w < (float)FW);
    const float m = valid ? 0.25f : 0.0f;
    const float w00 = (1.0f - hr) * (1.0f - wr) * m, w01 = (1.0f - hr) * wr * m;
    const float w10 = hr * (1.0f - wr) * m, w11 = hr * wr * m;
    const int c0 = g * (4 * CH_PER_WAVE) + wave * CH_PER_WAVE;
    const float* p = feat + ((size_t)(b * CH + c0)) * PLANE + (size_t)(hi * FW + wi);
    float* outp = out + ((size_t)n * CH + c0) * (POOL * POOL) + ph * POOL + pw;
    const bool do_store = (ph < POOL) && (pw < POOL);
#pragma unroll
    for (int dc = 0; dc < CH_PER_WAVE; ++dc) {
        float v = p[0] * w00 + p[1] * w01 + p[FW] * w10 + p[FW + 1] * w11;
        float s1 = v + __shfl_down(v, 1, 64);
        float s2 = s1 + __shfl_down(s1, 8, 64);
        if (do_store) __builtin_nontemporal_store(s2, outp);
        p += PLANE; outp += POOL * POOL;
    }
}

extern "C" void kernel_launch(void* const* d_in, const int* in_sizes, int n_in,
                              void* d_out, int out_size, void* d_ws, size_t ws_size,
                              hipStream_t stream) {
    const float* feat    = (const float*)d_in[0];  // (4,256,200,200) f32
    const float* rois    = (const float*)d_in[1];  // (1024,5) f32
    const float* scale_p = (const float*)d_in[2];  // scalar f32
    float*       out     = (float*)d_out;          // (1024,256,7,7) f32
    (void)in_sizes; (void)n_in; (void)out_size;

    const size_t ws_needed = (size_t)(BATCH + BATCH * NROI) * sizeof(int);
    if (ws_size >= ws_needed) {
        int* cnt = (int*)d_ws;
        int* idx = cnt + BATCH;
        hipLaunchKernelGGL(build_roi_lists, dim3(1), dim3(1024), 0, stream,
                           rois, cnt, idx);
        hipLaunchKernelGGL(roialign_lds_kernel, dim3(CH, BATCH), dim3(1024), 0,
                           stream, feat, rois, scale_p, cnt, idx, out);
    } else {
        hipLaunchKernelGGL(roialign_gather_kernel, dim3(NROI, CGROUPS), dim3(256),
                           0, stream, feat, rois, scale_p, out);
    }
}

// Round 7
// 266.900 us; speedup vs baseline: 1.1991x; 1.0233x over previous
//
#include <hip/hip_runtime.h>

// Problem constants (from reference setup_inputs)
#define BATCH 4
#define CH    256
#define FH    200
#define FW    200
#define NROI  1024
#define PLANE (FH * FW)     // 40000
#define POOL  7
#define NCG   16            // channel groups of 16 channels
#define CHPW  4             // channels per wave (4 waves x 4 ch = 16 ch/block)
#define SLOTS 256           // roi slots per set (loop handles cnt > SLOTS)
#define NSETS (BATCH * NCG) // 64 sets, each owns 16 planes = 2.56 MB (< 4 MB L2/XCD)

// ---------- pre-kernel: build per-image compacted roi index lists ----------
// ws layout: int cnt[BATCH]; int idx[BATCH][NROI];
__global__ __launch_bounds__(1024) void build_roi_lists(
    const float* __restrict__ rois, int* __restrict__ cnt, int* __restrict__ idx)
{
    __shared__ int lcnt[BATCH];
    const int tid = threadIdx.x;
    if (tid < BATCH) lcnt[tid] = 0;
    __syncthreads();
    const int b = (int)rois[tid * 5];
    const int pos = atomicAdd(&lcnt[b], 1);
    idx[(b << 10) + pos] = tid;
    __syncthreads();
    if (tid < BATCH) cnt[tid] = lcnt[tid];
}

// ---------- main kernel: L2-set-local global gather ------------------------
// set s = (image b, channel-group g): 16 planes = 2.56 MB, resident in ONE
// XCD's L2 (hw bid%8 ~ XCD round-robin, T1-style). Each plane belongs to
// exactly one set -> features fetched from HBM exactly once (~164 MB vs
// 284 MB in the unsorted version); all re-reads are ~200-cycle L2 hits,
// flipping the kernel from miss-latency-bound to line-throughput-bound.
// wave = 4 channels of one roi; lane = sample point (ph, pw); pooling via
// two shfl_down; validity + 0.25 folded into bilinear weights.
__global__ __launch_bounds__(256) void roialign_l2set_kernel(
    const float* __restrict__ feat,   // (B, C, H, W) f32
    const float* __restrict__ rois,   // (N, 5) f32
    const float* __restrict__ scale_p,
    const int*   __restrict__ cnt,    // [BATCH]
    const int*   __restrict__ idx,    // [BATCH][NROI]
    float* __restrict__ out)          // (N, C, 7, 7) f32
{
    const int bid = blockIdx.x;       // 64 sets * 256 slots = 16384 blocks
    const int xcd = bid & 7;          // hw round-robin: bid%8 ~ XCD id
    const int j   = bid >> 3;         // 0..2047 within this XCD
    const int s   = xcd + 8 * (j >> 8);   // set 0..63: 8 sets per XCD
    const int w   = j & 255;              // roi slot within set
    const int b   = s >> 4;           // image
    const int g   = s & 15;           // channel group

    const int tid  = threadIdx.x;
    const int wave = tid >> 6;
    const int lane = tid & 63;
    const int ph   = lane >> 3;       // sample row 0..7
    const int pw   = lane & 7;        // sample col 0..7
    const bool do_store = (ph < POOL) && (pw < POOL);

    const float scale = scale_p[0];
    const int cntb = __builtin_amdgcn_readfirstlane(cnt[b]);
    const int c0   = (g << 4) + (wave << 2);   // this wave's first channel

    for (int w0 = w; w0 < cntb; w0 += SLOTS) {
        const int n = __builtin_amdgcn_readfirstlane(idx[(b << 10) + w0]);

        // roi row: n is SGPR -> scalar loads, broadcast free
        const float x1 = rois[n * 5 + 1] * scale;
        const float y1 = rois[n * 5 + 2] * scale;
        const float x2 = rois[n * 5 + 3] * scale;
        const float y2 = rois[n * 5 + 4] * scale;

        // matches reference: max(span+1, 0) / (AH-1)
        const float bin_h = fmaxf(y2 - y1 + 1.0f, 0.0f) * (1.0f / 7.0f);
        const float bin_w = fmaxf(x2 - x1 + 1.0f, 0.0f) * (1.0f / 7.0f);

        const float h    = y1 + (float)ph * bin_h;
        const float ww   = x1 + (float)pw * bin_w;
        const float hs_f = fminf(floorf(h), (float)(FH - 2));
        const float ws_f = fminf(floorf(ww), (float)(FW - 2));
        const float hr   = h - hs_f;          // may exceed [0,1] at edges (ref too)
        const float wr   = ww - ws_f;
        const int   hi   = (int)fmaxf(hs_f, 0.0f);   // [0,198] -> loads in-bounds
        const int   wi   = (int)fmaxf(ws_f, 0.0f);   // [0,198]
        const bool  valid = (h >= 0.0f) && (h < (float)FH) &&
                            (ww >= 0.0f) && (ww < (float)FW);
        const float m = valid ? 0.25f : 0.0f; // fold validity + pool scale

        const float w00 = (1.0f - hr) * (1.0f - wr) * m;
        const float w01 = (1.0f - hr) * wr * m;
        const float w10 = hr * (1.0f - wr) * m;
        const float w11 = hr * wr * m;

        const float* p = feat + ((size_t)(b * CH + c0)) * PLANE
                              + (size_t)(hi * FW + wi);
        float* outp = out + ((size_t)n * CH + c0) * (POOL * POOL)
                          + ph * POOL + pw;

        // phase 1: issue all 16 gathers (4 ch x 4 corners) -> registers
        float g00[CHPW], g01[CHPW], g10[CHPW], g11[CHPW];
#pragma unroll
        for (int dc = 0; dc < CHPW; ++dc) {
            const float* q = p + (size_t)dc * PLANE;
            g00[dc] = q[0];
            g01[dc] = q[1];
            g10[dc] = q[FW];
            g11[dc] = q[FW + 1];
        }
        __builtin_amdgcn_sched_barrier(0);

        // phase 2: weight, 2x2 avg-pool via shuffles, store
#pragma unroll
        for (int dc = 0; dc < CHPW; ++dc) {
            float v  = g00[dc] * w00 + g01[dc] * w01
                     + g10[dc] * w10 + g11[dc] * w11;
            float s1 = v + __shfl_down(v, 1, 64);
            float s2 = s1 + __shfl_down(s1, 8, 64);
            if (do_store)
                __builtin_nontemporal_store(s2, outp + dc * (POOL * POOL));
        }
    }
}

// ---------- fallback (R4 global-gather) if ws is too small -----------------
#define CGROUPS 8
#define CH_PER_WAVE 8
__global__ __launch_bounds__(256) void roialign_gather_kernel(
    const float* __restrict__ feat, const float* __restrict__ rois,
    const float* __restrict__ scale_p, float* __restrict__ out)
{
    const int n = blockIdx.x, g = blockIdx.y, tid = threadIdx.x;
    const int wave = tid >> 6, lane = tid & 63;
    const int ph = lane >> 3, pw = lane & 7;
    const float scale = scale_p[0];
    const int   b  = (int)rois[n * 5 + 0];
    const float x1 = rois[n * 5 + 1] * scale, y1 = rois[n * 5 + 2] * scale;
    const float x2 = rois[n * 5 + 3] * scale, y2 = rois[n * 5 + 4] * scale;
    const float bin_h = fmaxf(y2 - y1 + 1.0f, 0.0f) / 7.0f;
    const float bin_w = fmaxf(x2 - x1 + 1.0f, 0.0f) / 7.0f;
    const float h = y1 + (float)ph * bin_h, w = x1 + (float)pw * bin_w;
    const float hs_f = fminf(floorf(h), (float)(FH - 2));
    const float ws_f = fminf(floorf(w), (float)(FW - 2));
    const float hr = h - hs_f, wr = w - ws_f;
    const int hi = (int)fmaxf(hs_f, 0.0f), wi = (int)fmaxf(ws_f, 0.0f);
    const bool valid = (h >= 0.0f) && (h < (float)FH) && (w >= 0.0f) && (w < (float)FW);
    const float m = valid ? 0.25f : 0.0f;
    const float w00 = (1.0f - hr) * (1.0f - wr) * m, w01 = (1.0f - hr) * wr * m;
    const float w10 = hr * (1.0f - wr) * m, w11 = hr * wr * m;
    const int c0 = g * (4 * CH_PER_WAVE) + wave * CH_PER_WAVE;
    const float* p = feat + ((size_t)(b * CH + c0)) * PLANE + (size_t)(hi * FW + wi);
    float* outp = out + ((size_t)n * CH + c0) * (POOL * POOL) + ph * POOL + pw;
    const bool do_store = (ph < POOL) && (pw < POOL);
#pragma unroll
    for (int dc = 0; dc < CH_PER_WAVE; ++dc) {
        float v = p[0] * w00 + p[1] * w01 + p[FW] * w10 + p[FW + 1] * w11;
        float s1 = v + __shfl_down(v, 1, 64);
        float s2 = s1 + __shfl_down(s1, 8, 64);
        if (do_store) __builtin_nontemporal_store(s2, outp);
        p += PLANE; outp += POOL * POOL;
    }
}

extern "C" void kernel_launch(void* const* d_in, const int* in_sizes, int n_in,
                              void* d_out, int out_size, void* d_ws, size_t ws_size,
                              hipStream_t stream) {
    const float* feat    = (const float*)d_in[0];  // (4,256,200,200) f32
    const float* rois    = (const float*)d_in[1];  // (1024,5) f32
    const float* scale_p = (const float*)d_in[2];  // scalar f32
    float*       out     = (float*)d_out;          // (1024,256,7,7) f32
    (void)in_sizes; (void)n_in; (void)out_size;

    const size_t ws_needed = (size_t)(BATCH + BATCH * NROI) * sizeof(int);
    if (ws_size >= ws_needed) {
        int* cnt = (int*)d_ws;
        int* idx = cnt + BATCH;
        hipLaunchKernelGGL(build_roi_lists, dim3(1), dim3(1024), 0, stream,
                           rois, cnt, idx);
        hipLaunchKernelGGL(roialign_l2set_kernel, dim3(NSETS * SLOTS), dim3(256),
                           0, stream, feat, rois, scale_p, cnt, idx, out);
    } else {
        hipLaunchKernelGGL(roialign_gather_kernel, dim3(NROI, CGROUPS), dim3(256),
                           0, stream, feat, rois, scale_p, out);
    }
}